// Round 7
// baseline (220.764 us; speedup 1.0000x reference)
//
#include <hip/hip_runtime.h>
#include <stdint.h>

#define T_ROWS 1500000
#define N_ROWS 2000000
#define N_SEL  1048576
#define G_CNT  (N_SEL/4)
#define LB     (N_ROWS - N_SEL)
#define TILE   4096
#define NBLK   ((N_ROWS + TILE - 1)/TILE)     // 489
#define GSTR   512                             // padded gH row stride (16B-aligned rows, L2-friendly)
#define THREADS 512
#define WAVES  8
#define WTILE  (TILE/WAVES)                    // 512
#define WROUNDS (WTILE/64)                     // 8
#define BINS   256
#define NB_MX  ((T_ROWS + THREADS - 1)/THREADS)

static_assert((uint64_t)NBLK * TILE >= N_ROWS, "tile coverage");
static_assert(T_ROWS < (1 << 21), "tp fits 21 bits");
static_assert((LB * 4) % 16 == 0, "finalize uint4 alignment");
static_assert(NBLK <= GSTR, "gH row stride");

// code = (descending-orderable key << 32) | (flag!=0 << 21) | tp.
// LSD radix over bits [32,64) is stable -> ties keep original (index-ascending)
// order == jnp.argsort(-bt). Payload carries everything finalize needs.
// build also emits the pass-0 per-tile histogram (kd already in regs) and mxtab.
__global__ __launch_bounds__(THREADS) void build_all(
        const float* __restrict__ nb, const float* __restrict__ td,
        uint64_t* __restrict__ codes, float* __restrict__ mxtab,
        uint32_t* __restrict__ gH) {
    const int b = blockIdx.x;
    if (b >= NBLK) {
        int i = (b - NBLK) * THREADS + threadIdx.x;
        if (i < T_ROWS) {
            float4 r = *(const float4*)(td + (size_t)i * 4);
            mxtab[i] = fmaxf(r.y, fmaxf(r.z, r.w));
        }
        return;
    }
    __shared__ uint32_t h[BINS];
    const int t = threadIdx.x;
    const int lane = t & 63;
    if (t < BINS) h[t] = 0;
    __syncthreads();
    const int base = b * TILE;
    #pragma unroll
    for (int r = 0; r < TILE / THREADS; ++r) {
        int i = base + r * THREADS + t;
        bool active = (i < N_ROWS);
        uint32_t kd = 0;
        if (active) {
            const float* row = nb + (size_t)i * 5;
            uint32_t u = __float_as_uint(row[1]);
            uint32_t ku = (u & 0x80000000u) ? ~u : (u | 0x80000000u); // asc uint == asc float
            kd = ~ku;                                                 // asc uint == desc float
            uint32_t tp = (uint32_t)(int)row[0];                      // exact: integral f32
            uint32_t fl = (row[4] != 0.0f) ? 1u : 0u;
            codes[i] = ((uint64_t)kd << 32) | (fl << 21) | tp;
        }
        uint32_t d = kd & (BINS - 1);       // pass-0 digit
        uint64_t m = __ballot(active ? 1 : 0);
        #pragma unroll
        for (int bb = 0; bb < 8; ++bb) {
            uint64_t x = __ballot((active && ((d >> bb) & 1u)) ? 1 : 0);
            m = ((d >> bb) & 1u) ? (m & x) : (m & ~x);
        }
        int ldr = __ffsll((unsigned long long)m) - 1;
        if (active && lane == ldr) atomicAdd(&h[d], (uint32_t)__popcll(m));
    }
    __syncthreads();
    if (t < BINS) gH[(size_t)t * GSTR + b] = h[t];
}

// SHIFT32: shift within the HIGH u32 of the code (8/16/24) — load 4B not 8B.
template <int SHIFT32>
__global__ __launch_bounds__(THREADS) void radix_hist(
        const uint64_t* __restrict__ src, uint32_t* __restrict__ gH) {
    __shared__ uint32_t h[BINS];
    const int t = threadIdx.x;
    const int lane = t & 63;
    if (t < BINS) h[t] = 0;
    __syncthreads();
    const int base = blockIdx.x * TILE;
    const uint32_t* s32 = (const uint32_t*)src;
    #pragma unroll
    for (int r = 0; r < TILE / THREADS; ++r) {
        int i = base + r * THREADS + t;
        bool active = (i < N_ROWS);
        uint32_t d = 0;
        if (active) d = (s32[2 * (size_t)i + 1] >> SHIFT32) & (BINS - 1);
        uint64_t m = __ballot(active ? 1 : 0);
        #pragma unroll
        for (int bb = 0; bb < 8; ++bb) {
            uint64_t x = __ballot((active && ((d >> bb) & 1u)) ? 1 : 0);
            m = ((d >> bb) & 1u) ? (m & x) : (m & ~x);
        }
        int ldr = __ffsll((unsigned long long)m) - 1;
        if (active && lane == ldr) atomicAdd(&h[d], (uint32_t)__popcll(m));
    }
    __syncthreads();
    if (t < BINS) gH[(size_t)t * GSTR + blockIdx.x] = h[t];
}

template <int SHIFT, bool LAST>
__global__ __launch_bounds__(THREADS) void radix_scatter(
        const uint64_t* __restrict__ src, uint64_t* __restrict__ dst,
        uint32_t* __restrict__ dst32, const uint32_t* __restrict__ gH) {
    __shared__ uint64_t tileS[TILE];             // 32 KB
    __shared__ uint32_t cnt32[BINS * WAVES];     // 8 KB  per-(digit,wave) counts/cursors
    __shared__ uint32_t writeBase[BINS];
    __shared__ uint32_t wpT[WAVES], wpL[WAVES];
    const int t = threadIdx.x;
    const int lane = t & 63;
    const int w = t >> 6;
    const int blk = blockIdx.x;
    const int base = blk * TILE;
    const int tileCount = (N_ROWS - base < TILE) ? (N_ROWS - base) : TILE;

    #pragma unroll
    for (int k = t; k < BINS * WAVES; k += THREADS) cnt32[k] = 0u;
    __syncthreads();

    // ---- phase A: per-wave digit counts via ballot match; save (rank,ldr,cnt) per round
    uint64_t creg[WROUNDS];
    uint32_t meta[WROUNDS];
    const uint64_t below = (lane == 0) ? 0ull : (~0ull >> (64 - lane));
    #pragma unroll
    for (int r = 0; r < WROUNDS; ++r) {
        int idx = base + w * WTILE + r * 64 + lane;
        bool active = (idx < N_ROWS);
        uint64_t c = active ? src[idx] : 0ull;
        creg[r] = c;
        uint32_t d = (uint32_t)(c >> SHIFT) & (BINS - 1);
        uint64_t m = __ballot(active ? 1 : 0);
        #pragma unroll
        for (int bb = 0; bb < 8; ++bb) {
            uint64_t x = __ballot((active && ((d >> bb) & 1u)) ? 1 : 0);
            m = ((d >> bb) & 1u) ? (m & x) : (m & ~x);
        }
        int ldr = __ffsll((unsigned long long)m) - 1;
        uint32_t cnt = (uint32_t)__popcll(m);
        uint32_t rank = (uint32_t)__popcll(m & below);
        meta[r] = rank | ((uint32_t)(ldr < 0 ? 0 : ldr) << 8) | (cnt << 16);
        if (active && lane == ldr)
            atomicAdd(&cnt32[d * WAVES + w], cnt);
    }

    // ---- phase B0: self-service prefixes (replaces the rowscan kernel).
    // gH rows are raw per-tile counts; gH is 512 KB -> L2-resident across blocks.
    // Overlaps the phase-A barrier wait of the other waves.
    uint32_t rp = 0, tot = 0, lc = 0;
    if (t < BINS) {
        const uint32_t* row = gH + (size_t)t * GSTR;
        lc = row[blk];
        int i = 0;
        for (; i + 4 <= (NBLK & ~3); i += 4) {
            uint4 v = *(const uint4*)(row + i);
            uint32_t s4 = v.x + v.y + v.z + v.w;
            tot += s4;
            if (i + 4 <= blk) rp += s4;
            else {
                if (i + 0 < blk) rp += v.x;
                if (i + 1 < blk) rp += v.y;
                if (i + 2 < blk) rp += v.z;
                if (i + 3 < blk) rp += v.w;
            }
        }
        for (; i < NBLK; ++i) {
            uint32_t v = row[i];
            tot += v;
            if (i < blk) rp += v;
        }
    }
    __syncthreads();   // phase A cnt32 complete

    // ---- phase B1: dual block-exclusive scans over digits (tot -> exT, lc -> exL)
    uint32_t sT = tot, sL = lc;
    #pragma unroll
    for (int off = 1; off < 64; off <<= 1) {
        uint32_t aT = __shfl_up(sT, off, 64);
        uint32_t aL = __shfl_up(sL, off, 64);
        if (lane >= off) { sT += aT; sL += aL; }
    }
    if (lane == 63) { wpT[w] = sT; wpL[w] = sL; }
    __syncthreads();
    uint32_t exT = sT - tot, exL = sL - lc;
    #pragma unroll
    for (int wv = 0; wv < WAVES; ++wv) if (wv < w) { exT += wpT[wv]; exL += wpL[wv]; }

    // ---- phase B2: writeBase + per-wave cursors (thread t owns digit t exclusively)
    if (t < BINS) {
        writeBase[t] = exT + rp - exL;
        uint32_t run = exL;
        #pragma unroll
        for (int wv = 0; wv < WAVES; ++wv) {
            uint32_t c0 = cnt32[t * WAVES + wv];
            cnt32[t * WAVES + wv] = run;
            run += c0;
        }
    }
    __syncthreads();

    // ---- phase C: ballot-free — leader atomicAdd on cursor, shfl, LDS scatter
    #pragma unroll
    for (int r = 0; r < WROUNDS; ++r) {
        int idx = base + w * WTILE + r * 64 + lane;
        bool active = (idx < N_ROWS);
        uint64_t c = creg[r];
        uint32_t d = (uint32_t)(c >> SHIFT) & (BINS - 1);
        uint32_t mt = meta[r];
        uint32_t rank = mt & 0xFFu;
        int ldr = (int)((mt >> 8) & 0xFFu);
        uint32_t cnt = mt >> 16;
        uint32_t before = 0;
        if (active && lane == ldr)
            before = atomicAdd(&cnt32[d * WAVES + w], cnt);
        before = __shfl(before, ldr, 64);
        if (active) tileS[before + rank] = c;
    }
    __syncthreads();

    // ---- write-out: consecutive sorted positions share digit -> 128B avg segments
    #pragma unroll
    for (int r = 0; r < TILE / THREADS; ++r) {
        int p = r * THREADS + t;
        if (p < tileCount) {
            uint64_t c = tileS[p];
            uint32_t d = (uint32_t)(c >> SHIFT) & (BINS - 1);
            uint32_t g = writeBase[d] + p;
            if (!LAST) {
                dst[(size_t)g] = c;
            } else if (g >= LB) {        // only selected range is read; payload only
                dst32[g] = (uint32_t)c;
            }
        }
    }
}

__global__ void finalize(const uint32_t* __restrict__ pay, const float* __restrict__ td,
                         const float* __restrict__ mxtab, float* __restrict__ out) {
    int g = blockIdx.x * 256 + threadIdx.x;
    if (g >= G_CNT) return;
    uint4 p4 = *(const uint4*)(pay + LB + (size_t)g * 4);
    uint32_t cs[4] = {p4.x, p4.y, p4.z, p4.w};
    float maxmin = -100000.0f;
    int maxindex = -100;
    #pragma unroll
    for (int j = 0; j < 4; ++j) {
        int tp = (int)(cs[j] & 0x1FFFFFu);
        bool re1 = ((cs[j] >> 21) & 1u) != 0u;
        float mx = mxtab[tp];
        bool gt = (mx > maxmin);
        if (re1 == gt) { maxmin = mx; maxindex = tp; }
    }
    int mi = maxindex < 0 ? 0 : maxindex;   // clip lower bound; upper never binds
    float4 row = *(const float4*)(td + (size_t)mi * 4);
    *(float4*)(out + (size_t)g * 4) = row;
}

extern "C" void kernel_launch(void* const* d_in, const int* in_sizes, int n_in,
                              void* d_out, int out_size, void* d_ws, size_t ws_size,
                              hipStream_t stream) {
    const float* td = (const float*)d_in[0];
    const float* nb = (const float*)d_in[1];
    float* out = (float*)d_out;
    uint8_t* ws = (uint8_t*)d_ws;

    // layout: mxtab 6MB | gH 256*512*4 = 512KB | A 16MB | B 16MB  (ends ~38.5 MiB)
    float*    mxtab = (float*)(ws);
    uint32_t* gH    = (uint32_t*)(ws + (size_t)6 * 1024 * 1024);
    uint64_t* A     = (uint64_t*)(ws + (size_t)8 * 1024 * 1024);
    uint64_t* B     = (uint64_t*)(ws + (size_t)8 * 1024 * 1024 + 16000512);

    build_all<<<NBLK + NB_MX, THREADS, 0, stream>>>(nb, td, A, mxtab, gH);

    // pass 0: code bits [32,40) — histogram fused into build; prefixes in-block
    radix_scatter<32, false><<<NBLK, THREADS, 0, stream>>>(A, B, nullptr, gH);

    // pass 1: bits [40,48)
    radix_hist<8><<<NBLK, THREADS, 0, stream>>>(B, gH);
    radix_scatter<40, false><<<NBLK, THREADS, 0, stream>>>(B, A, nullptr, gH);

    // pass 2: bits [48,56)
    radix_hist<16><<<NBLK, THREADS, 0, stream>>>(A, gH);
    radix_scatter<48, false><<<NBLK, THREADS, 0, stream>>>(A, B, nullptr, gH);

    // pass 3: bits [56,64) — slim: payload-only u32 writes into selected range
    radix_hist<24><<<NBLK, THREADS, 0, stream>>>(B, gH);
    radix_scatter<56, true><<<NBLK, THREADS, 0, stream>>>(B, nullptr, (uint32_t*)A, gH);

    finalize<<<(G_CNT + 255) / 256, 256, 0, stream>>>((const uint32_t*)A, td, mxtab, out);
}

// Round 8
// 142.148 us; speedup vs baseline: 1.5531x; 1.5531x over previous
//
#include <hip/hip_runtime.h>
#include <stdint.h>

#define T_ROWS 1500000
#define N_ROWS 2000000
#define N_SEL  1048576
#define G_CNT  (N_SEL/4)
#define LB     (N_ROWS - N_SEL)
#define TILE   4096
#define NBLK   ((N_ROWS + TILE - 1)/TILE)     // 489
#define THREADS 512
#define WAVES  8
#define WTILE  (TILE/WAVES)                    // 512
#define WROUNDS (WTILE/64)                     // 8
#define BINS   256
#define CHUNK  ((NBLK + WAVES - 1)/WAVES)      // 62 tiles per wave in prefix pass
#define NB_MX  ((T_ROWS + THREADS - 1)/THREADS)

static_assert((uint64_t)NBLK * TILE >= N_ROWS, "tile coverage");
static_assert(T_ROWS < (1 << 21), "tp fits 21 bits");
static_assert((LB * 4) % 16 == 0, "finalize uint4 alignment");

// code = (descending-orderable key << 32) | (flag!=0 << 21) | tp.
// LSD radix over bits [32,64) is stable -> ties keep original (index-ascending)
// order == jnp.argsort(-bt). Payload carries everything finalize needs.
// gT layout is TILE-MAJOR: gT[tile*256 + digit] (coalesced writes AND reads).
__global__ __launch_bounds__(THREADS) void build_all(
        const float* __restrict__ nb, const float* __restrict__ td,
        uint64_t* __restrict__ codes, float* __restrict__ mxtab,
        uint32_t* __restrict__ gT) {
    const int b = blockIdx.x;
    if (b >= NBLK) {
        int i = (b - NBLK) * THREADS + threadIdx.x;
        if (i < T_ROWS) {
            float4 r = *(const float4*)(td + (size_t)i * 4);
            mxtab[i] = fmaxf(r.y, fmaxf(r.z, r.w));
        }
        return;
    }
    __shared__ uint32_t h[BINS];
    const int t = threadIdx.x;
    if (t < BINS) h[t] = 0;
    __syncthreads();
    const int base = b * TILE;
    #pragma unroll
    for (int r = 0; r < TILE / THREADS; ++r) {
        int i = base + r * THREADS + t;
        if (i < N_ROWS) {
            const float* row = nb + (size_t)i * 5;
            uint32_t u = __float_as_uint(row[1]);
            uint32_t ku = (u & 0x80000000u) ? ~u : (u | 0x80000000u); // asc uint == asc float
            uint32_t kd = ~ku;                                        // asc uint == desc float
            uint32_t tp = (uint32_t)(int)row[0];                      // exact: integral f32
            uint32_t fl = (row[4] != 0.0f) ? 1u : 0u;
            codes[i] = ((uint64_t)kd << 32) | (fl << 21) | tp;
            // pass-0 digit = low mantissa bits -> uniform -> plain atomics are cheap
            atomicAdd(&h[kd & (BINS - 1)], 1u);
        }
    }
    __syncthreads();
    if (t < BINS) gT[(size_t)b * BINS + t] = h[t];
}

// Uniform-digit histogram (mantissa bytes): plain LDS atomics.
template <int SHIFT32>
__global__ __launch_bounds__(THREADS) void radix_hist_u(
        const uint64_t* __restrict__ src, uint32_t* __restrict__ gT) {
    __shared__ uint32_t h[BINS];
    const int t = threadIdx.x;
    if (t < BINS) h[t] = 0;
    __syncthreads();
    const int base = blockIdx.x * TILE;
    const uint32_t* s32 = (const uint32_t*)src;
    #pragma unroll
    for (int r = 0; r < TILE / THREADS; ++r) {
        int i = base + r * THREADS + t;
        if (i < N_ROWS)
            atomicAdd(&h[(s32[2 * (size_t)i + 1] >> SHIFT32) & (BINS - 1)], 1u);
    }
    __syncthreads();
    if (t < BINS) gT[(size_t)blockIdx.x * BINS + t] = h[t];
}

// Skewed-digit histogram (top byte: sign+exponent): ballot-leader counting.
template <int SHIFT32>
__global__ __launch_bounds__(THREADS) void radix_hist_s(
        const uint64_t* __restrict__ src, uint32_t* __restrict__ gT) {
    __shared__ uint32_t h[BINS];
    const int t = threadIdx.x;
    const int lane = t & 63;
    if (t < BINS) h[t] = 0;
    __syncthreads();
    const int base = blockIdx.x * TILE;
    const uint32_t* s32 = (const uint32_t*)src;
    #pragma unroll
    for (int r = 0; r < TILE / THREADS; ++r) {
        int i = base + r * THREADS + t;
        bool active = (i < N_ROWS);
        uint32_t d = 0;
        if (active) d = (s32[2 * (size_t)i + 1] >> SHIFT32) & (BINS - 1);
        uint64_t m = __ballot(active ? 1 : 0);
        #pragma unroll
        for (int bb = 0; bb < 8; ++bb) {
            uint64_t x = __ballot((active && ((d >> bb) & 1u)) ? 1 : 0);
            m = ((d >> bb) & 1u) ? (m & x) : (m & ~x);
        }
        int ldr = __ffsll((unsigned long long)m) - 1;
        if (active && lane == ldr) atomicAdd(&h[d], (uint32_t)__popcll(m));
    }
    __syncthreads();
    if (t < BINS) gT[(size_t)blockIdx.x * BINS + t] = h[t];
}

template <int SHIFT, bool LAST>
__global__ __launch_bounds__(THREADS) void radix_scatter(
        const uint64_t* __restrict__ src, uint64_t* __restrict__ dst,
        uint32_t* __restrict__ dst32, const uint32_t* __restrict__ gT) {
    __shared__ uint64_t tileS[TILE];             // 32 KB; first 16 KB aliased as pB0 in B0/B1
    __shared__ uint32_t cnt32[BINS * WAVES];     // 8 KB  per-(digit,wave) counts/cursors
    __shared__ uint32_t writeBase[BINS];
    __shared__ uint32_t wpT[WAVES], wpL[WAVES];
    uint32_t* pB0 = (uint32_t*)tileS;            // [0,2048): tot partials; [2048,4096): rp partials

    const int t = threadIdx.x;
    const int lane = t & 63;
    const int w = t >> 6;
    const int blk = blockIdx.x;
    const int base = blk * TILE;
    const int tileCount = (N_ROWS - base < TILE) ? (N_ROWS - base) : TILE;

    // early: own tile's per-digit count (coalesced; used as scan input in B1)
    uint32_t lcv = 0;
    if (t < BINS) lcv = gT[(size_t)blk * BINS + t];

    #pragma unroll
    for (int k = t; k < BINS * WAVES; k += THREADS) cnt32[k] = 0u;
    __syncthreads();

    // ---- phase A: per-wave digit counts via ballot match; save (rank,ldr,cnt) per round
    uint64_t creg[WROUNDS];
    uint32_t meta[WROUNDS];
    const uint64_t below = (lane == 0) ? 0ull : (~0ull >> (64 - lane));
    #pragma unroll
    for (int r = 0; r < WROUNDS; ++r) {
        int idx = base + w * WTILE + r * 64 + lane;
        bool active = (idx < N_ROWS);
        uint64_t c = active ? src[idx] : 0ull;
        creg[r] = c;
        uint32_t d = (uint32_t)(c >> SHIFT) & (BINS - 1);
        uint64_t m = __ballot(active ? 1 : 0);
        #pragma unroll
        for (int bb = 0; bb < 8; ++bb) {
            uint64_t x = __ballot((active && ((d >> bb) & 1u)) ? 1 : 0);
            m = ((d >> bb) & 1u) ? (m & x) : (m & ~x);
        }
        int ldr = __ffsll((unsigned long long)m) - 1;
        uint32_t cnt = (uint32_t)__popcll(m);
        uint32_t rank = (uint32_t)__popcll(m & below);
        meta[r] = rank | ((uint32_t)(ldr < 0 ? 0 : ldr) << 8) | (cnt << 16);
        if (active && lane == ldr)
            atomicAdd(&cnt32[d * WAVES + w], cnt);
    }

    // ---- phase B0: self-service prefixes, COALESCED tile-major reads.
    // wave w sums tiles [w*CHUNK, ...); lane l owns digits 4l..4l+3 (uint4 loads:
    // 64 lanes x 16 B = 1 KB consecutive per instruction).
    {
        uint32_t totw[4] = {0, 0, 0, 0}, rpw[4] = {0, 0, 0, 0};
        int i0 = w * CHUNK;
        int i1 = (i0 + CHUNK < NBLK) ? (i0 + CHUNK) : NBLK;
        for (int i = i0; i < i1; ++i) {
            uint4 v = *(const uint4*)(gT + (size_t)i * BINS + lane * 4);
            totw[0] += v.x; totw[1] += v.y; totw[2] += v.z; totw[3] += v.w;
            if (i < blk) { rpw[0] += v.x; rpw[1] += v.y; rpw[2] += v.z; rpw[3] += v.w; }
        }
        *(uint4*)(pB0 + (size_t)w * BINS + lane * 4) =
            make_uint4(totw[0], totw[1], totw[2], totw[3]);
        *(uint4*)(pB0 + 2048 + (size_t)w * BINS + lane * 4) =
            make_uint4(rpw[0], rpw[1], rpw[2], rpw[3]);
    }
    __syncthreads();   // phase A cnt32 + B0 partials complete

    // ---- phase B1: reduce partials (tot, rp); dual block-exclusive scan (tot, lcv)
    uint32_t tot = 0, rp = 0;
    if (t < BINS) {
        #pragma unroll
        for (int wv = 0; wv < WAVES; ++wv) {
            tot += pB0[wv * BINS + t];
            rp  += pB0[2048 + wv * BINS + t];
        }
    }
    uint32_t sT = tot, sL = lcv;
    #pragma unroll
    for (int off = 1; off < 64; off <<= 1) {
        uint32_t aT = __shfl_up(sT, off, 64);
        uint32_t aL = __shfl_up(sL, off, 64);
        if (lane >= off) { sT += aT; sL += aL; }
    }
    if (lane == 63) { wpT[w] = sT; wpL[w] = sL; }
    __syncthreads();
    uint32_t exT = sT - tot, exL = sL - lcv;
    #pragma unroll
    for (int wv = 0; wv < WAVES; ++wv) if (wv < w) { exT += wpT[wv]; exL += wpL[wv]; }

    // ---- phase B2: writeBase + per-wave cursors (thread t owns digit t exclusively)
    if (t < BINS) {
        writeBase[t] = exT + rp - exL;
        uint32_t run = exL;
        #pragma unroll
        for (int wv = 0; wv < WAVES; ++wv) {
            uint32_t c0 = cnt32[t * WAVES + wv];
            cnt32[t * WAVES + wv] = run;
            run += c0;
        }
    }
    __syncthreads();   // cursors ready; pB0 (=tileS) reads done -> phase C may write tileS

    // ---- phase C: ballot-free — leader atomicAdd on cursor, shfl, LDS scatter
    #pragma unroll
    for (int r = 0; r < WROUNDS; ++r) {
        int idx = base + w * WTILE + r * 64 + lane;
        bool active = (idx < N_ROWS);
        uint64_t c = creg[r];
        uint32_t d = (uint32_t)(c >> SHIFT) & (BINS - 1);
        uint32_t mt = meta[r];
        uint32_t rank = mt & 0xFFu;
        int ldr = (int)((mt >> 8) & 0xFFu);
        uint32_t cnt = mt >> 16;
        uint32_t before = 0;
        if (active && lane == ldr)
            before = atomicAdd(&cnt32[d * WAVES + w], cnt);
        before = __shfl(before, ldr, 64);
        if (active) tileS[before + rank] = c;
    }
    __syncthreads();

    // ---- write-out: consecutive sorted positions share digit -> 128B avg segments
    #pragma unroll
    for (int r = 0; r < TILE / THREADS; ++r) {
        int p = r * THREADS + t;
        if (p < tileCount) {
            uint64_t c = tileS[p];
            uint32_t d = (uint32_t)(c >> SHIFT) & (BINS - 1);
            uint32_t g = writeBase[d] + p;
            if (!LAST) {
                dst[(size_t)g] = c;
            } else if (g >= LB) {        // only selected range is read; payload only
                dst32[g] = (uint32_t)c;
            }
        }
    }
}

__global__ void finalize(const uint32_t* __restrict__ pay, const float* __restrict__ td,
                         const float* __restrict__ mxtab, float* __restrict__ out) {
    int g = blockIdx.x * 256 + threadIdx.x;
    if (g >= G_CNT) return;
    uint4 p4 = *(const uint4*)(pay + LB + (size_t)g * 4);
    uint32_t cs[4] = {p4.x, p4.y, p4.z, p4.w};
    float maxmin = -100000.0f;
    int maxindex = -100;
    #pragma unroll
    for (int j = 0; j < 4; ++j) {
        int tp = (int)(cs[j] & 0x1FFFFFu);
        bool re1 = ((cs[j] >> 21) & 1u) != 0u;
        float mx = mxtab[tp];
        bool gt = (mx > maxmin);
        if (re1 == gt) { maxmin = mx; maxindex = tp; }
    }
    int mi = maxindex < 0 ? 0 : maxindex;   // clip lower bound; upper never binds
    float4 row = *(const float4*)(td + (size_t)mi * 4);
    *(float4*)(out + (size_t)g * 4) = row;
}

extern "C" void kernel_launch(void* const* d_in, const int* in_sizes, int n_in,
                              void* d_out, int out_size, void* d_ws, size_t ws_size,
                              hipStream_t stream) {
    const float* td = (const float*)d_in[0];
    const float* nb = (const float*)d_in[1];
    float* out = (float*)d_out;
    uint8_t* ws = (uint8_t*)d_ws;

    // layout: mxtab 6MB | gT 489*256*4 ~0.5MB | A 16MB | B 16MB  (ends ~40 MiB)
    float*    mxtab = (float*)(ws);
    uint32_t* gT    = (uint32_t*)(ws + (size_t)6 * 1024 * 1024);
    uint64_t* A     = (uint64_t*)(ws + (size_t)8 * 1024 * 1024);
    uint64_t* B     = (uint64_t*)(ws + (size_t)24 * 1024 * 1024);

    build_all<<<NBLK + NB_MX, THREADS, 0, stream>>>(nb, td, A, mxtab, gT);

    // pass 0: code bits [32,40) — histogram fused into build; prefixes in-block
    radix_scatter<32, false><<<NBLK, THREADS, 0, stream>>>(A, B, nullptr, gT);

    // pass 1: bits [40,48) — uniform digit
    radix_hist_u<8><<<NBLK, THREADS, 0, stream>>>(B, gT);
    radix_scatter<40, false><<<NBLK, THREADS, 0, stream>>>(B, A, nullptr, gT);

    // pass 2: bits [48,56) — uniform digit
    radix_hist_u<16><<<NBLK, THREADS, 0, stream>>>(A, gT);
    radix_scatter<48, false><<<NBLK, THREADS, 0, stream>>>(A, B, nullptr, gT);

    // pass 3: bits [56,64) — skewed digit; slim payload-only writes in selected range
    radix_hist_s<24><<<NBLK, THREADS, 0, stream>>>(B, gT);
    radix_scatter<56, true><<<NBLK, THREADS, 0, stream>>>(B, nullptr, (uint32_t*)A, gT);

    finalize<<<(G_CNT + 255) / 256, 256, 0, stream>>>((const uint32_t*)A, td, mxtab, out);
}